// Round 5
// baseline (146.762 us; speedup 1.0000x reference)
//
#include <hip/hip_runtime.h>
#include <hip/hip_bf16.h>

// Problem constants (from reference setup_inputs)
#define B_  16
#define S_  1024
#define D_  300
#define DP  320          // D padded to multiple of 32 with zeros
#define K_  64           // hidden_set_size == compressed dim
#define O_  256          // outputs per batch
#define M_  (B_*S_)      // 16384 rows (b,s)

typedef __attribute__((ext_vector_type(8)))  short s8b;    // 8 x bf16 (4 VGPRs)
typedef __attribute__((ext_vector_type(4)))  float f32x4;
typedef __attribute__((ext_vector_type(16))) float f32x16;

#define MFMA16(a,b,c) __builtin_amdgcn_mfma_f32_16x16x32_bf16((a),(b),(c),0,0,0)
#define MFMA32(a,b,c) __builtin_amdgcn_mfma_f32_32x32x16_bf16((a),(b),(c),0,0,0)

__device__ __forceinline__ unsigned short bf16_bits(float f) {
    return __builtin_bit_cast(unsigned short, __float2bfloat16(f));
}

// ---------------------------------------------------------------------------
// Kernel 0: f32 -> bf16 for W and H, plus zero-init of out.
//   blocks [0, 512)   : H flat -> Hb [O*K*K], 8 el/thread
//   blocks [512, 522) : W rows -> Wb [64][DP] zero-padded, 40 thr/row
//   block  522        : out[16*256] = 0  (k_fused accumulates with atomics)
// ---------------------------------------------------------------------------
#define H_BLK  512    // 256*64*64/8/256
#define W_BLK  10     // 64*320/8/256
__global__ __launch_bounds__(256) void k_convert(
        const float* __restrict__ W, const float* __restrict__ H,
        __hip_bfloat16* __restrict__ Wb, __hip_bfloat16* __restrict__ Hb,
        float* __restrict__ out) {
    int bx = blockIdx.x, t = threadIdx.x;
    if (bx < H_BLK) {                        // H flat (no padding)
        int g = (bx * 256 + t) * 8;
        float4 f0 = *(const float4*)(H + g);
        float4 f1 = *(const float4*)(H + g + 4);
        union { unsigned short us[8]; uint4 q; } pk;
        pk.us[0]=bf16_bits(f0.x); pk.us[1]=bf16_bits(f0.y);
        pk.us[2]=bf16_bits(f0.z); pk.us[3]=bf16_bits(f0.w);
        pk.us[4]=bf16_bits(f1.x); pk.us[5]=bf16_bits(f1.y);
        pk.us[6]=bf16_bits(f1.z); pk.us[7]=bf16_bits(f1.w);
        *(uint4*)(Hb + g) = pk.q;
        return;
    }
    if (bx == H_BLK + W_BLK) {               // zero out[4096]
        float4 z = {0.f,0.f,0.f,0.f};
        float4* o4 = (float4*)out;
#pragma unroll
        for (int i = 0; i < 4; ++i) o4[t * 4 + i] = z;
        return;
    }
    int g = (bx - H_BLK) * 256 + t;          // W rows, 40 threads/row
    int r = g / 40, c = (g - r * 40) * 8;
    const float* src = W + (size_t)r * D_;
    float v[8];
    if (c + 8 <= D_) {
        float4 f0 = *(const float4*)(src + c);
        float4 f1 = *(const float4*)(src + c + 4);
        v[0]=f0.x; v[1]=f0.y; v[2]=f0.z; v[3]=f0.w;
        v[4]=f1.x; v[5]=f1.y; v[6]=f1.z; v[7]=f1.w;
    } else {
#pragma unroll
        for (int j = 0; j < 8; ++j) v[j] = (c + j < D_) ? src[c + j] : 0.0f;
    }
    union { unsigned short us[8]; uint4 q; } pk;
#pragma unroll
    for (int j = 0; j < 8; ++j) pk.us[j] = bf16_bits(v[j]);
    *(uint4*)(Wb + (size_t)r * DP + c) = pk.q;
}

// ---------------------------------------------------------------------------
// Kernel 1: compress GEMM, A read directly from f32 Xs (convert in regs).
// Xc[m][k] = sum_d Xs[m][d]*Wb[k][d] + bias[k].
// Block = 256 thr (4 waves); block tile 16 rows x 64 cols; wave = 16x16.
// ---------------------------------------------------------------------------
__global__ __launch_bounds__(256) void k_compress(
        const float* __restrict__ Xs,
        const __hip_bfloat16* __restrict__ Wb,
        const float* __restrict__ bias,
        __hip_bfloat16* __restrict__ Xc) {
    int tid  = threadIdx.x;
    int w    = tid >> 6, lane = tid & 63;
    int q    = lane >> 4, r = lane & 15;
    int row0 = blockIdx.x * 16;
    int col0 = w * 16;

    f32x4 acc0 = {0.f,0.f,0.f,0.f}, acc1 = {0.f,0.f,0.f,0.f};
    const float*          arow = Xs + (size_t)(row0 + r) * D_;
    const __hip_bfloat16* brow = Wb + (size_t)(col0 + r) * DP;
    const float4 z4 = {0.f,0.f,0.f,0.f};

#pragma unroll
    for (int ks = 0; ks < 10; ++ks) {
        int k0 = ks * 32 + q * 8;
        float4 f0 = (k0     < D_) ? *(const float4*)(arow + k0)     : z4;
        float4 f1 = (k0 + 4 < D_) ? *(const float4*)(arow + k0 + 4) : z4;
        union { unsigned short us[8]; s8b v; } pk;
        pk.us[0]=bf16_bits(f0.x); pk.us[1]=bf16_bits(f0.y);
        pk.us[2]=bf16_bits(f0.z); pk.us[3]=bf16_bits(f0.w);
        pk.us[4]=bf16_bits(f1.x); pk.us[5]=bf16_bits(f1.y);
        pk.us[6]=bf16_bits(f1.z); pk.us[7]=bf16_bits(f1.w);
        s8b b = __builtin_bit_cast(s8b, *(const uint4*)(brow + k0));
        if (ks & 1) acc1 = MFMA16(pk.v, b, acc1);
        else        acc0 = MFMA16(pk.v, b, acc0);
    }
    // C/D layout: col = lane&15 (out-k), row = quad*4 + i (bs)
#pragma unroll
    for (int i = 0; i < 4; ++i) {
        int orow = row0 + q * 4 + i;
        int c    = col0 + r;
        Xc[(size_t)orow * K_ + c] =
            __float2bfloat16(acc0[i] + acc1[i] + bias[c]);
    }
}

// ---------------------------------------------------------------------------
// Kernel 2: fused bipartite GEMM + relu + max-over-n + sum-over-s.
// NO LDS, NO BARRIERS: B-fragments are read directly from global (L1/L2).
// Per t, the wave's 4 dwordx4 loads fully consume 32 contiguous 128B lines
// (one per bs-row), so L1 coalesces them; compiler pipelines loads across
// t-iterations with fine-grained vmcnt since nothing blocks on a barrier.
// 32x32x16 MFMA, A = Hb (n rows), B = Xc (bs cols):
//   C col = lane&31 = bs, row = (reg&3)+8*(reg>>2)+4*(lane>>5) = n.
// Cross-half shuffles are batched 4-per-group (one exposed latency per 4 t).
// Block = 256 thr (4 waves, one o each), 512 bs-rows (16 t-tiles).
// Grid: 16 batches x 64 o-quads x 2 bs-halves = 2048 blocks (8/CU).
// Each (b,o) gets 2 atomicAdds; out zero-initialized by k_convert.
// ---------------------------------------------------------------------------
__global__ __launch_bounds__(256) void k_fused(
        const __hip_bfloat16* __restrict__ Xc,
        const __hip_bfloat16* __restrict__ Hb,
        float* __restrict__ out) {
    int tid   = threadIdx.x;
    int w     = tid >> 6, lane = tid & 63;
    int half  = lane >> 5, l31 = lane & 31;
    int bx    = blockIdx.x;
    int batch = bx >> 7;          // 0..15
    int oq    = (bx >> 1) & 63;   // 0..63
    int sh    = bx & 1;           // 0..1 : which 512-row half
    int o     = oq * 4 + w;

    // Preload A fragments (Hb, this wave's o): 2 n-tiles x 4 k-steps.
    // A layout: row = lane&31 (n), k = (lane>>5)*8 + j.
    s8b af[2][4];
#pragma unroll
    for (int nt = 0; nt < 2; ++nt) {
        const __hip_bfloat16* hrow =
            Hb + (size_t)(o * 64 + nt * 32 + l31) * 64 + half * 8;
#pragma unroll
        for (int ks = 0; ks < 4; ++ks)
            af[nt][ks] = __builtin_bit_cast(s8b, *(const uint4*)(hrow + ks * 16));
    }

    const __hip_bfloat16* xbase =
        Xc + ((size_t)batch * S_ + (size_t)sh * 512) * K_;

    float total = 0.0f;
    for (int tt = 0; tt < 4; ++tt) {
        float vt[4];
#pragma unroll
        for (int j = 0; j < 4; ++j) {
            int t  = tt * 4 + j;
            int rr = t * 32 + l31;
            // B layout: col = lane&31 (bs row rr), k = (lane>>5)*8 + jj;
            // step ks covers k = 16*ks .. 16*ks+15.
            const __hip_bfloat16* xrow = xbase + (size_t)rr * K_ + half * 8;
            s8b bf[4];
#pragma unroll
            for (int ks = 0; ks < 4; ++ks)
                bf[ks] = __builtin_bit_cast(s8b, *(const uint4*)(xrow + ks * 16));

            f32x16 a0 = {0.f,0.f,0.f,0.f,0.f,0.f,0.f,0.f,
                         0.f,0.f,0.f,0.f,0.f,0.f,0.f,0.f};
            f32x16 a1 = a0;
#pragma unroll
            for (int ks = 0; ks < 4; ++ks) {
                a0 = MFMA32(af[0][ks], bf[ks], a0);
                a1 = MFMA32(af[1][ks], bf[ks], a1);
            }
            float m0 = fmaxf(fmaxf(a0[0], a0[1]),  fmaxf(a0[2], a0[3]));
            float m1 = fmaxf(fmaxf(a0[4], a0[5]),  fmaxf(a0[6], a0[7]));
            float m2 = fmaxf(fmaxf(a0[8], a0[9]),  fmaxf(a0[10], a0[11]));
            float m3 = fmaxf(fmaxf(a0[12], a0[13]),fmaxf(a0[14], a0[15]));
            float n0 = fmaxf(fmaxf(a1[0], a1[1]),  fmaxf(a1[2], a1[3]));
            float n1 = fmaxf(fmaxf(a1[4], a1[5]),  fmaxf(a1[6], a1[7]));
            float n2 = fmaxf(fmaxf(a1[8], a1[9]),  fmaxf(a1[10], a1[11]));
            float n3 = fmaxf(fmaxf(a1[12], a1[13]),fmaxf(a1[14], a1[15]));
            vt[j] = fmaxf(fmaxf(fmaxf(m0, m1), fmaxf(m2, m3)),
                          fmaxf(fmaxf(n0, n1), fmaxf(n2, n3)));
        }
        // Batched cross-half merges: 4 back-to-back shuffles overlap, then
        // relu + accumulate.
#pragma unroll
        for (int j = 0; j < 4; ++j)
            vt[j] = fmaxf(vt[j], __shfl_xor(vt[j], 32));
#pragma unroll
        for (int j = 0; j < 4; ++j)
            total += fmaxf(vt[j], 0.0f);
    }
    // Sum over the 32 bs columns (halves hold identical totals).
    total += __shfl_xor(total, 1);
    total += __shfl_xor(total, 2);
    total += __shfl_xor(total, 4);
    total += __shfl_xor(total, 8);
    total += __shfl_xor(total, 16);
    if (lane == 0) atomicAdd(out + batch * O_ + o, total);
}

// ---------------------------------------------------------------------------
extern "C" void kernel_launch(void* const* d_in, const int* in_sizes, int n_in,
                              void* d_out, int out_size, void* d_ws, size_t ws_size,
                              hipStream_t stream) {
    const float* Xs   = (const float*)d_in[0];   // [16,1024,300]
    const float* W    = (const float*)d_in[1];   // [64,300]
    const float* bias = (const float*)d_in[2];   // [64]
    const float* H    = (const float*)d_in[3];   // [256,64,64]
    float* out = (float*)d_out;                  // [16,256] f32

    char* ws = (char*)d_ws;
    __hip_bfloat16* Wb = (__hip_bfloat16*)(ws);               //     40,960 B
    __hip_bfloat16* Hb = (__hip_bfloat16*)(ws + 40960);       //  2,097,152 B
    __hip_bfloat16* Xc = (__hip_bfloat16*)(ws + 2138112);     //  2,097,152 B

    k_convert <<<H_BLK + W_BLK + 1, 256, 0, stream>>>(W, H, Wb, Hb, out);
    k_compress<<<M_ / 16, 256, 0, stream>>>(Xs, Wb, bias, Xc);
    k_fused   <<<B_ * (O_ / 4) * 2, 256, 0, stream>>>(Xc, Hb, out);
}

// Round 6
// 108.225 us; speedup vs baseline: 1.3561x; 1.3561x over previous
//
#include <hip/hip_runtime.h>
#include <hip/hip_bf16.h>

// Problem constants (from reference setup_inputs)
#define B_  16
#define S_  1024
#define D_  300
#define DP  320          // D padded to multiple of 32 with zeros
#define K_  64           // hidden_set_size == compressed dim
#define O_  256          // outputs per batch
#define M_  (B_*S_)      // 16384 rows (b,s)

#define LROW 80          // LDS row stride in elements (160 B) -> conflict-free

typedef __attribute__((ext_vector_type(8)))  short s8b;    // 8 x bf16 (4 VGPRs)
typedef __attribute__((ext_vector_type(4)))  float f32x4;
typedef __attribute__((ext_vector_type(16))) float f32x16;

#define MFMA16(a,b,c) __builtin_amdgcn_mfma_f32_16x16x32_bf16((a),(b),(c),0,0,0)
#define MFMA32(a,b,c) __builtin_amdgcn_mfma_f32_32x32x16_bf16((a),(b),(c),0,0,0)

__device__ __forceinline__ unsigned short bf16_bits(float f) {
    return __builtin_bit_cast(unsigned short, __float2bfloat16(f));
}

// ---------------------------------------------------------------------------
// Kernel 0: f32 -> bf16 for W and H, plus zero-init of out.
//   blocks [0, 512)   : H flat -> Hb [O*K*K], 8 el/thread
//   blocks [512, 522) : W rows -> Wb [64][DP] zero-padded, 40 thr/row
//   block  522        : out[16*256] = 0  (k_fused accumulates with atomics)
// ---------------------------------------------------------------------------
#define H_BLK  512    // 256*64*64/8/256
#define W_BLK  10     // 64*320/8/256
__global__ __launch_bounds__(256) void k_convert(
        const float* __restrict__ W, const float* __restrict__ H,
        __hip_bfloat16* __restrict__ Wb, __hip_bfloat16* __restrict__ Hb,
        float* __restrict__ out) {
    int bx = blockIdx.x, t = threadIdx.x;
    if (bx < H_BLK) {                        // H flat (no padding)
        int g = (bx * 256 + t) * 8;
        float4 f0 = *(const float4*)(H + g);
        float4 f1 = *(const float4*)(H + g + 4);
        union { unsigned short us[8]; uint4 q; } pk;
        pk.us[0]=bf16_bits(f0.x); pk.us[1]=bf16_bits(f0.y);
        pk.us[2]=bf16_bits(f0.z); pk.us[3]=bf16_bits(f0.w);
        pk.us[4]=bf16_bits(f1.x); pk.us[5]=bf16_bits(f1.y);
        pk.us[6]=bf16_bits(f1.z); pk.us[7]=bf16_bits(f1.w);
        *(uint4*)(Hb + g) = pk.q;
        return;
    }
    if (bx == H_BLK + W_BLK) {               // zero out[4096]
        float4 z = {0.f,0.f,0.f,0.f};
        float4* o4 = (float4*)out;
#pragma unroll
        for (int i = 0; i < 4; ++i) o4[t * 4 + i] = z;
        return;
    }
    int g = (bx - H_BLK) * 256 + t;          // W rows, 40 threads/row
    int r = g / 40, c = (g - r * 40) * 8;
    const float* src = W + (size_t)r * D_;
    float v[8];
    if (c + 8 <= D_) {
        float4 f0 = *(const float4*)(src + c);
        float4 f1 = *(const float4*)(src + c + 4);
        v[0]=f0.x; v[1]=f0.y; v[2]=f0.z; v[3]=f0.w;
        v[4]=f1.x; v[5]=f1.y; v[6]=f1.z; v[7]=f1.w;
    } else {
#pragma unroll
        for (int j = 0; j < 8; ++j) v[j] = (c + j < D_) ? src[c + j] : 0.0f;
    }
    union { unsigned short us[8]; uint4 q; } pk;
#pragma unroll
    for (int j = 0; j < 8; ++j) pk.us[j] = bf16_bits(v[j]);
    *(uint4*)(Wb + (size_t)r * DP + c) = pk.q;
}

// ---------------------------------------------------------------------------
// Kernel 1: compress GEMM, A read directly from f32 Xs (convert in regs).
// Xc[m][k] = sum_d Xs[m][d]*Wb[k][d] + bias[k].
// Block = 256 thr (4 waves); block tile 16 rows x 64 cols; wave = 16x16.
// ---------------------------------------------------------------------------
__global__ __launch_bounds__(256) void k_compress(
        const float* __restrict__ Xs,
        const __hip_bfloat16* __restrict__ Wb,
        const float* __restrict__ bias,
        __hip_bfloat16* __restrict__ Xc) {
    int tid  = threadIdx.x;
    int w    = tid >> 6, lane = tid & 63;
    int q    = lane >> 4, r = lane & 15;
    int row0 = blockIdx.x * 16;
    int col0 = w * 16;

    f32x4 acc0 = {0.f,0.f,0.f,0.f}, acc1 = {0.f,0.f,0.f,0.f};
    const float*          arow = Xs + (size_t)(row0 + r) * D_;
    const __hip_bfloat16* brow = Wb + (size_t)(col0 + r) * DP;
    const float4 z4 = {0.f,0.f,0.f,0.f};

#pragma unroll
    for (int ks = 0; ks < 10; ++ks) {
        int k0 = ks * 32 + q * 8;
        float4 f0 = (k0     < D_) ? *(const float4*)(arow + k0)     : z4;
        float4 f1 = (k0 + 4 < D_) ? *(const float4*)(arow + k0 + 4) : z4;
        union { unsigned short us[8]; s8b v; } pk;
        pk.us[0]=bf16_bits(f0.x); pk.us[1]=bf16_bits(f0.y);
        pk.us[2]=bf16_bits(f0.z); pk.us[3]=bf16_bits(f0.w);
        pk.us[4]=bf16_bits(f1.x); pk.us[5]=bf16_bits(f1.y);
        pk.us[6]=bf16_bits(f1.z); pk.us[7]=bf16_bits(f1.w);
        s8b b = __builtin_bit_cast(s8b, *(const uint4*)(brow + k0));
        if (ks & 1) acc1 = MFMA16(pk.v, b, acc1);
        else        acc0 = MFMA16(pk.v, b, acc0);
    }
    // C/D layout: col = lane&15 (out-k), row = quad*4 + i (bs)
#pragma unroll
    for (int i = 0; i < 4; ++i) {
        int orow = row0 + q * 4 + i;
        int c    = col0 + r;
        Xc[(size_t)orow * K_ + c] =
            __float2bfloat16(acc0[i] + acc1[i] + bias[c]);
    }
}

// ---------------------------------------------------------------------------
// Kernel 2: fused bipartite GEMM + relu + max-over-n + sum-over-s.
// Block = 4 waves (one o each) over 512 bs-rows: 8 slices of 64 rows staged
// in double-buffered LDS (row stride 80 elem = 160 B -> provably conflict-free
// ds_read_b128/ds_write_b128), register prefetch of slice s+1 during compute
// of slice s, ONE barrier per slice.  Global staging reads are 8 fully-
// consumed 128B lines per instruction.
// 32x32x16 MFMA, A = Hb (n rows), B = Xc (bs cols):
//   C col = lane&31 = bs, row = (reg&3)+8*(reg>>2)+4*(lane>>5) = n.
// Grid: 16 batches x 64 o-quads x 2 s-halves = 2048 blocks; LDS 20,480 B
// allows 8 blocks/CU, so barrier stalls overlap across blocks.
// ---------------------------------------------------------------------------
__global__ __launch_bounds__(256, 4) void k_fused(
        const __hip_bfloat16* __restrict__ Xc,
        const __hip_bfloat16* __restrict__ Hb,
        float* __restrict__ out) {
    __shared__ __hip_bfloat16 lx[2][64 * LROW];   // 2 x 10,240 B
    int tid   = threadIdx.x;
    int w     = tid >> 6, lane = tid & 63;
    int half  = lane >> 5, l31 = lane & 31;
    int bx    = blockIdx.x;
    int batch = bx >> 7;          // 0..15
    int oq    = (bx >> 1) & 63;   // 0..63
    int sh    = bx & 1;           // 0..1 : which 512-row half
    int o     = oq * 4 + w;

    // Preload A fragments (Hb, this wave's o): 2 n-tiles x 4 k-steps.
    // A layout: row = lane&31 (n), k = (lane>>5)*8 + j.
    s8b af[2][4];
#pragma unroll
    for (int nt = 0; nt < 2; ++nt) {
        const __hip_bfloat16* hrow =
            Hb + (size_t)(o * 64 + nt * 32 + l31) * 64 + half * 8;
#pragma unroll
        for (int ks = 0; ks < 4; ++ks)
            af[nt][ks] = __builtin_bit_cast(s8b, *(const uint4*)(hrow + ks * 16));
    }

    const __hip_bfloat16* xbase =
        Xc + ((size_t)batch * S_ + (size_t)sh * 512) * K_;

    // Staging map: thread t -> rows (t>>3), (t>>3)+32; 16B chunk (t&7).
    int sr = tid >> 3, sc = tid & 7;

    // Stage slice 0 into buffer 0.
#pragma unroll
    for (int i = 0; i < 2; ++i) {
        int r = sr + i * 32;
        uint4 v = *(const uint4*)(xbase + (size_t)r * K_ + sc * 8);
        *(uint4*)(&lx[0][r * LROW + sc * 8]) = v;
    }
    __syncthreads();

    float total = 0.0f;
    for (int s = 0; s < 8; ++s) {
        uint4 npf[2];
        if (s < 7) {                           // prefetch slice s+1 -> regs
            const __hip_bfloat16* nsrc = xbase + (size_t)(s + 1) * 64 * K_;
#pragma unroll
            for (int i = 0; i < 2; ++i)
                npf[i] = *(const uint4*)(nsrc + (size_t)(sr + i * 32) * K_ + sc * 8);
        }
        const __hip_bfloat16* buf = lx[s & 1];
#pragma unroll
        for (int t = 0; t < 2; ++t) {
            int rr = t * 32 + l31;
            // B layout: col = lane&31 (bs row rr), k = (lane>>5)*8 + j;
            // step ks covers k = 16*ks .. 16*ks+15 -> chunk 2*ks+half.
            s8b bf[4];
#pragma unroll
            for (int ks = 0; ks < 4; ++ks)
                bf[ks] = __builtin_bit_cast(s8b,
                    *(const uint4*)(&buf[rr * LROW + (2 * ks + half) * 8]));

            f32x16 a0 = {0.f,0.f,0.f,0.f,0.f,0.f,0.f,0.f,
                         0.f,0.f,0.f,0.f,0.f,0.f,0.f,0.f};
            f32x16 a1 = a0;
#pragma unroll
            for (int ks = 0; ks < 4; ++ks) {
                a0 = MFMA32(af[0][ks], bf[ks], a0);
                a1 = MFMA32(af[1][ks], bf[ks], a1);
            }
            // Max over 32 in-lane n-values: 4 max3-fusable chains.
            float m0 = fmaxf(fmaxf(a0[0], a0[1]), a0[2]);
            m0 = fmaxf(fmaxf(m0, a0[3]), a0[4]);
            m0 = fmaxf(fmaxf(m0, a0[5]), a0[6]);
            m0 = fmaxf(m0, a0[7]);
            float m1 = fmaxf(fmaxf(a0[8], a0[9]), a0[10]);
            m1 = fmaxf(fmaxf(m1, a0[11]), a0[12]);
            m1 = fmaxf(fmaxf(m1, a0[13]), a0[14]);
            m1 = fmaxf(m1, a0[15]);
            float m2 = fmaxf(fmaxf(a1[0], a1[1]), a1[2]);
            m2 = fmaxf(fmaxf(m2, a1[3]), a1[4]);
            m2 = fmaxf(fmaxf(m2, a1[5]), a1[6]);
            m2 = fmaxf(m2, a1[7]);
            float m3 = fmaxf(fmaxf(a1[8], a1[9]), a1[10]);
            m3 = fmaxf(fmaxf(m3, a1[11]), a1[12]);
            m3 = fmaxf(fmaxf(m3, a1[13]), a1[14]);
            m3 = fmaxf(m3, a1[15]);
            float v = fmaxf(fmaxf(fmaxf(m0, m1), fmaxf(m2, m3)), 0.0f);
            v = fmaxf(v, __shfl_xor(v, 32));   // other half's 32 n-rows
            total += v;                        // lane's bs col = rr (replicated)
        }
        if (s < 7) {                           // publish slice s+1, 1 barrier
#pragma unroll
            for (int i = 0; i < 2; ++i) {
                int r = sr + i * 32;
                *(uint4*)(&lx[(s + 1) & 1][r * LROW + sc * 8]) = npf[i];
            }
            __syncthreads();
        }
    }
    // Sum over the 32 bs columns (halves hold identical totals).
    total += __shfl_xor(total, 1);
    total += __shfl_xor(total, 2);
    total += __shfl_xor(total, 4);
    total += __shfl_xor(total, 8);
    total += __shfl_xor(total, 16);
    if (lane == 0) atomicAdd(out + batch * O_ + o, total);
}

// ---------------------------------------------------------------------------
extern "C" void kernel_launch(void* const* d_in, const int* in_sizes, int n_in,
                              void* d_out, int out_size, void* d_ws, size_t ws_size,
                              hipStream_t stream) {
    const float* Xs   = (const float*)d_in[0];   // [16,1024,300]
    const float* W    = (const float*)d_in[1];   // [64,300]
    const float* bias = (const float*)d_in[2];   // [64]
    const float* H    = (const float*)d_in[3];   // [256,64,64]
    float* out = (float*)d_out;                  // [16,256] f32

    char* ws = (char*)d_ws;
    __hip_bfloat16* Wb = (__hip_bfloat16*)(ws);               //     40,960 B
    __hip_bfloat16* Hb = (__hip_bfloat16*)(ws + 40960);       //  2,097,152 B
    __hip_bfloat16* Xc = (__hip_bfloat16*)(ws + 2138112);     //  2,097,152 B

    k_convert <<<H_BLK + W_BLK + 1, 256, 0, stream>>>(W, H, Wb, Hb, out);
    k_compress<<<M_ / 16, 256, 0, stream>>>(Xs, Wb, bias, Xc);
    k_fused   <<<B_ * (O_ / 4) * 2, 256, 0, stream>>>(Xc, Hb, out);
}